// Round 4
// baseline (147.208 us; speedup 1.0000x reference)
//
#include <hip/hip_runtime.h>

// Problem constants
static constexpr int NB   = 128;   // batch
static constexpr int NCIN = 64;    // input channels
static constexpr int NG   = 8;     // groups
static constexpr int NH   = 14;    // spatial
static constexpr int NP   = 16;    // mixed width
static constexpr int HH   = NH * NH;       // 196
static constexpr int LROW = 20;    // padded t4s row (l in [-2,17])

// LDS layout (float offsets)
static constexpr int OFF_W2 = 0;       // [8][5][32]  = 1280
static constexpr int OFF_WC = 1280;    // [2][8][32]  =  512
static constexpr int OFF_T4 = 1792;    // [8][16][20] = 2560
static constexpr int OFF_XS = 4352;    // [8 j4][126 glst] float4 = 4032 floats
static constexpr int OFF_WM = 8384;    // [16 jw][16 p] float4    = 1024 floats
static constexpr int LDS_FLOATS = 9408;   // 37,632 B -> 4 blocks/CU
// output staging reuses lds[0 .. 512*15) = 7680 floats after conv phase

// ---------------------------------------------------------------------------
// Fully fused kernel. block = (b, o), 256 threads.
//   Phase A/B: stage x[b,:,:,o_src,:] (28 KB) + wmix in LDS, compute the t4
//              slice t4s[g][p][l] = sum_j x[j][g][l]*wmix[j][p] in registers
//              (j split in 2 halves to halve xs LDS; half-1 loads prefetched
//              into regs during phase B0 -> HBM latency hidden under FMA).
//   Conv phase: verified 5-tap conv (reads t4s/w2s/wcs).
//   Output: LDS-staged transpose. Staging map addr = c*15 + ((n+2*(c>>5))%15)
//           is INJECTIVE (each c owns its 15-slot; rotation permutes within)
//           and de-conflicts the dc=32 writer-lane collisions (rot step 2).
// ---------------------------------------------------------------------------
__global__ __launch_bounds__(256) void fused_kernel(const float* __restrict__ x,
                                                    const float* __restrict__ wconv,
                                                    const float* __restrict__ wmix,
                                                    float* __restrict__ out) {
    __shared__ __align__(16) float lds[LDS_FLOATS];
    float*  w2s = lds + OFF_W2;
    float*  wcs = lds + OFF_WC;
    float*  t4s = lds + OFF_T4;
    float4* xs4 = reinterpret_cast<float4*>(lds + OFF_XS);
    float4* wm4 = reinterpret_cast<float4*>(lds + OFF_WM);

    const int tid   = threadIdx.x;
    const int b     = blockIdx.x / NH;
    const int o     = blockIdx.x % NH;
    const int o_src = (o + NH - 1) % NH;

    const float* xb = x + (size_t)b * (NCIN * NG * HH) + o_src * NH;

    // ---- issue x half-0 loads (j = 0..31) into regs ----
    float xr[14];
#pragma unroll
    for (int r = 0; r < 14; r++) {
        int idx = r * 256 + tid;                 // 0..3583
        int j   = idx / 112;                     // 0..31
        int gl  = idx % 112;                     // g*14 + l
        xr[r] = xb[(size_t)j * (NG * HH) + (gl / 14) * HH + (gl % 14)];
    }

    // ---- stage wmix transposed: lds[OFF_WM + (jw*16+p)*4 + jj] = wmix[(jw*4+jj)*16+p]
#pragma unroll
    for (int r = 0; r < 4; r++) {                // 1024 entries
        int idx = r * 256 + tid;
        int jw  = idx >> 6;
        int p   = (idx >> 2) & 15;
        int jj  = idx & 3;
        lds[OFF_WM + idx] = wmix[(jw * 4 + jj) * NP + p];
    }
    // ---- W2[g][d][j] = sum_{i+k==d} wconv[g][i][k][j]
#pragma unroll
    for (int r = 0; r < 5; r++) {                // 1280 entries
        int idx = r * 256 + tid;
        int g   = idx / 160;
        int di  = (idx / 32) % 5;
        int j   = idx % 32;
        int ilo = di > 2 ? di - 2 : 0;
        int ihi = di < 2 ? di : 2;
        float s = 0.f;
        for (int i = ilo; i <= ihi; i++) {
            int k = di - i;
            s += wconv[((g * 3 + i) * 3 + k) * 32 + j];
        }
        w2s[idx] = s;
    }
    // ---- corrections: wcs[0][g][j]=wconv[g][0][2][j]; wcs[1][g][j]=wconv[g][2][0][j]
#pragma unroll
    for (int r = 0; r < 2; r++) {                // 512 entries
        int idx = r * 256 + tid;
        int sel = idx / 256;
        int g   = (idx / 32) % 8;
        int j   = idx % 32;
        wcs[idx] = wconv[(g * 9 + (sel ? 6 : 2)) * 32 + j];
    }
    // ---- zero t4s pad columns l2 in {0,1,16,17,18,19}
#pragma unroll
    for (int r = 0; r < 3; r++) {                // 768 entries
        int idx = r * 256 + tid;
        int gp  = idx / 6;
        int s   = idx % 6;
        int l2  = (s < 2) ? s : (14 + s);
        t4s[gp * LROW + l2] = 0.f;
    }
    // ---- write x half-0 into xs (bank-swizzled: glst = gl + gl/8)
#pragma unroll
    for (int r = 0; r < 14; r++) {
        int idx  = r * 256 + tid;
        int j    = idx / 112;
        int gl   = idx % 112;
        int glst = gl + (gl >> 3);
        lds[OFF_XS + (((j >> 2) * 126 + glst) << 2) + (j & 3)] = xr[r];
    }
    __syncthreads();

    // ---- prefetch x half-1 (j = 32..63) into regs; overlaps with B0 compute
#pragma unroll
    for (int r = 0; r < 14; r++) {
        int idx = r * 256 + tid;
        int j   = 32 + idx / 112;
        int gl  = idx % 112;
        xr[r] = xb[(size_t)j * (NG * HH) + (gl / 14) * HH + (gl % 14)];
    }

    // ---- phase B: t4 slice, 224 active threads, tile = 2 gl x 4 p
    const int  glp   = tid >> 2;                 // 0..63 (active < 56)
    const int  pq    = tid & 3;                  // p-quad
    const bool bact  = (glp < 56);
    const int  glst0 = glp + (glp >> 3);
    const int  glst1 = glst0 + 63;               // (glp+56) + ((glp+56)>>3)
    float accA[4] = {0.f, 0.f, 0.f, 0.f};
    float accB[4] = {0.f, 0.f, 0.f, 0.f};

    if (bact) {
#pragma unroll
        for (int j4 = 0; j4 < 8; j4++) {
            float4 xa = xs4[j4 * 126 + glst0];
            float4 xv = xs4[j4 * 126 + glst1];
#pragma unroll
            for (int pp = 0; pp < 4; pp++) {
                float4 w = wm4[j4 * 16 + pq * 4 + pp];
                accA[pp] += xa.x * w.x + xa.y * w.y + xa.z * w.z + xa.w * w.w;
                accB[pp] += xv.x * w.x + xv.y * w.y + xv.z * w.z + xv.w * w.w;
            }
        }
    }
    __syncthreads();
    // ---- write x half-1 into xs
#pragma unroll
    for (int r = 0; r < 14; r++) {
        int idx  = r * 256 + tid;
        int j    = idx / 112;                    // local 0..31
        int gl   = idx % 112;
        int glst = gl + (gl >> 3);
        lds[OFF_XS + (((j >> 2) * 126 + glst) << 2) + (j & 3)] = xr[r];
    }
    __syncthreads();

    if (bact) {
#pragma unroll
        for (int j4 = 0; j4 < 8; j4++) {
            float4 xa = xs4[j4 * 126 + glst0];
            float4 xv = xs4[j4 * 126 + glst1];
#pragma unroll
            for (int pp = 0; pp < 4; pp++) {
                float4 w = wm4[(8 + j4) * 16 + pq * 4 + pp];
                accA[pp] += xa.x * w.x + xa.y * w.y + xa.z * w.z + xa.w * w.w;
                accB[pp] += xv.x * w.x + xv.y * w.y + xv.z * w.z + xv.w * w.w;
            }
        }
        // ---- scatter t4 slice into conv layout t4s[(g*16+p)*20 + l+2]
        int g0 = glp / 14,        l0 = glp % 14;
        int g1 = (glp + 56) / 14, l1 = (glp + 56) % 14;
#pragma unroll
        for (int pp = 0; pp < 4; pp++) {
            t4s[(g0 * 16 + pq * 4 + pp) * LROW + l0 + 2] = accA[pp];
            t4s[(g1 * 16 + pq * 4 + pp) * LROW + l1 + 2] = accB[pp];
        }
    }
    __syncthreads();

    // ================= conv phase (verified structure, unchanged) ==========
    const int p  = tid & 15;
    const int jh = tid >> 4;        // 0..15
    const int jb = jh * 2;          // channels j = jb, jb+1

    float acc[NH][2];
#pragma unroll
    for (int n = 0; n < NH; n++) { acc[n][0] = 0.f; acc[n][1] = 0.f; }

    for (int g = 0; g < NG; g++) {
        float row[LROW];
        const float* rp = &t4s[(g * 16 + p) * LROW];
#pragma unroll
        for (int q = 0; q < 5; q++) {
            float4 v = *reinterpret_cast<const float4*>(rp + q * 4);
            row[q * 4 + 0] = v.x; row[q * 4 + 1] = v.y;
            row[q * 4 + 2] = v.z; row[q * 4 + 3] = v.w;
        }
#pragma unroll
        for (int di = 0; di < 5; di++) {
            float2 w = *reinterpret_cast<const float2*>(&w2s[(g * 5 + di) * 32 + jb]);
#pragma unroll
            for (int n = 0; n < NH; n++) {
                float rv = row[n + di];
                acc[n][0] += rv * w.x;
                acc[n][1] += rv * w.y;
            }
        }
        float2 c0 = *reinterpret_cast<const float2*>(&wcs[g * 32 + jb]);
        float2 c1 = *reinterpret_cast<const float2*>(&wcs[256 + g * 32 + jb]);
        float r2 = row[2], r15 = row[15];
        acc[0][0]  -= r2  * c0.x; acc[0][1]  -= r2  * c0.y;
        acc[13][0] -= r15 * c1.x; acc[13][1] -= r15 * c1.y;
    }

    __syncthreads();   // done with t4s/w2s/wcs; reuse lds[0..7680) as out stage

    // ---- stage all 512 channels: addr = c*15 + ((n + 2*(c>>5)) % 15)  (injective)
#pragma unroll
    for (int jj = 0; jj < 2; jj++) {
        int cl  = (jb + jj) * 16 + p;            // 0..511
        int rot = (cl >> 5) * 2;                 // 0,2,..,30 -> mod15 via wrap
        int sb  = cl * 15;
#pragma unroll
        for (int n = 0; n < NH; n++) {
            int rn = n + rot;
            rn -= (rn >= 15) ? 15 : 0;
            rn -= (rn >= 15) ? 15 : 0;           // rot up to 30: two wraps max
            lds[sb + rn] = acc[n][jj];
        }
    }
    __syncthreads();

    // ---- coalesced-ish write: contiguous 14-float runs per channel
    float* ob = out + (size_t)b * 512 * HH + (size_t)o * NH;
#pragma unroll
    for (int r = 0; r < 28; r++) {               // 7168 = 512*14
        int idx = r * 256 + tid;
        int c   = idx / 14;
        int n   = idx % 14;
        int rn  = n + (c >> 5) * 2;
        rn -= (rn >= 15) ? 15 : 0;
        rn -= (rn >= 15) ? 15 : 0;
        ob[(size_t)c * HH + n] = lds[c * 15 + rn];
    }
}

extern "C" void kernel_launch(void* const* d_in, const int* in_sizes, int n_in,
                              void* d_out, int out_size, void* d_ws, size_t ws_size,
                              hipStream_t stream) {
    const float* x     = (const float*)d_in[0];
    const float* wconv = (const float*)d_in[1];
    const float* wmix  = (const float*)d_in[2];
    float* out = (float*)d_out;
    (void)d_ws; (void)ws_size;

    // one block per (b, o)
    fused_kernel<<<NB * NH, 256, 0, stream>>>(x, wconv, wmix, out);
}

// Round 5
// 140.772 us; speedup vs baseline: 1.0457x; 1.0457x over previous
//
#include <hip/hip_runtime.h>

// Problem constants
static constexpr int NB   = 128;   // batch
static constexpr int NCIN = 64;    // input channels
static constexpr int NG   = 8;     // groups
static constexpr int NH   = 14;    // spatial
static constexpr int NP   = 16;    // mixed width
static constexpr int HH   = NH * NH;       // 196
static constexpr int LROW = 20;    // padded t4s row (l in [-2,17])

// LDS layout (float offsets)
static constexpr int OFF_W2 = 0;       // [8][5][32]  = 1280
static constexpr int OFF_WC = 1280;    // [2][8][32]  =  512
static constexpr int OFF_T4 = 1792;    // [8][16][20] = 2560
static constexpr int OFF_XS = 4352;    // [8 j4][126 glst] float4 = 4032 floats
static constexpr int LDS_FLOATS = 8384;   // 33,536 B (wm table eliminated)
// output staging reuses lds[0 .. 512*15) = 7680 floats after conv phase

// ---------------------------------------------------------------------------
// Fully fused kernel. block = (b, o), 256 threads.
//   Phase B rework (this round): wave w owns gl=(w&1)*64+lane and the
//   wave-UNIFORM p-half p0=(w>>1)*8 -> wmix[j*16+p] addresses are wave-
//   uniform -> s_load from K$ (zero LDS traffic). Cuts phase-B LDS reads
//   from 96 to 16 ds_read_b128 per thread and deletes the 4 KB wm staging.
//   xs layout/staging, conv phase, and the injective output rotation are
//   unchanged from the verified R4 kernel.
// ---------------------------------------------------------------------------
__global__ __launch_bounds__(256) void fused_kernel(const float* __restrict__ x,
                                                    const float* __restrict__ wconv,
                                                    const float* __restrict__ wmix,
                                                    float* __restrict__ out) {
    __shared__ __align__(16) float lds[LDS_FLOATS];
    float*  w2s = lds + OFF_W2;
    float*  wcs = lds + OFF_WC;
    float*  t4s = lds + OFF_T4;
    float4* xs4 = reinterpret_cast<float4*>(lds + OFF_XS);

    const int tid   = threadIdx.x;
    const int b     = blockIdx.x / NH;
    const int o     = blockIdx.x % NH;
    const int o_src = (o + NH - 1) % NH;

    const float* xb = x + (size_t)b * (NCIN * NG * HH) + o_src * NH;

    // ---- issue x half-0 loads (j = 0..31) into regs ----
    float xr[14];
#pragma unroll
    for (int r = 0; r < 14; r++) {
        int idx = r * 256 + tid;                 // 0..3583
        int j   = idx / 112;                     // 0..31
        int gl  = idx % 112;                     // g*14 + l
        xr[r] = xb[(size_t)j * (NG * HH) + (gl / 14) * HH + (gl % 14)];
    }

    // ---- W2[g][d][j] = sum_{i+k==d} wconv[g][i][k][j]
#pragma unroll
    for (int r = 0; r < 5; r++) {                // 1280 entries
        int idx = r * 256 + tid;
        int g   = idx / 160;
        int di  = (idx / 32) % 5;
        int j   = idx % 32;
        int ilo = di > 2 ? di - 2 : 0;
        int ihi = di < 2 ? di : 2;
        float s = 0.f;
        for (int i = ilo; i <= ihi; i++) {
            int k = di - i;
            s += wconv[((g * 3 + i) * 3 + k) * 32 + j];
        }
        w2s[idx] = s;
    }
    // ---- corrections: wcs[0][g][j]=wconv[g][0][2][j]; wcs[1][g][j]=wconv[g][2][0][j]
#pragma unroll
    for (int r = 0; r < 2; r++) {                // 512 entries
        int idx = r * 256 + tid;
        int sel = idx / 256;
        int g   = (idx / 32) % 8;
        int j   = idx % 32;
        wcs[idx] = wconv[(g * 9 + (sel ? 6 : 2)) * 32 + j];
    }
    // ---- zero t4s pad columns l2 in {0,1,16,17,18,19}
#pragma unroll
    for (int r = 0; r < 3; r++) {                // 768 entries
        int idx = r * 256 + tid;
        int gp  = idx / 6;
        int s   = idx % 6;
        int l2  = (s < 2) ? s : (14 + s);
        t4s[gp * LROW + l2] = 0.f;
    }
    // ---- write x half-0 into xs (bank-swizzled: glst = gl + gl/8)
#pragma unroll
    for (int r = 0; r < 14; r++) {
        int idx  = r * 256 + tid;
        int j    = idx / 112;
        int gl   = idx % 112;
        int glst = gl + (gl >> 3);
        lds[OFF_XS + (((j >> 2) * 126 + glst) << 2) + (j & 3)] = xr[r];
    }
    __syncthreads();

    // ---- prefetch x half-1 (j = 32..63) into regs; overlaps with B0 compute
#pragma unroll
    for (int r = 0; r < 14; r++) {
        int idx = r * 256 + tid;
        int j   = 32 + idx / 112;
        int gl  = idx % 112;
        xr[r] = xb[(size_t)j * (NG * HH) + (gl / 14) * HH + (gl % 14)];
    }

    // ---- phase B: wave w -> gl=(w&1)*64+lane, p-half=(w>>1) (wave-uniform)
    const int  wv   = tid >> 6;
    const int  glB  = ((wv & 1) << 6) + (tid & 63);      // 0..127
    const bool bact = (glB < 112);
    const int  p0   = __builtin_amdgcn_readfirstlane((tid >> 7) << 3);  // 0 or 8, SGPR
    const int  glst = glB + (glB >> 3);

    float am[8] = {0.f, 0.f, 0.f, 0.f, 0.f, 0.f, 0.f, 0.f};

    if (bact) {
#pragma unroll
        for (int j4 = 0; j4 < 8; j4++) {
            float4 xq = xs4[j4 * 126 + glst];
#pragma unroll
            for (int pp = 0; pp < 8; pp++) {
                const int p = p0 + pp;           // wave-uniform -> s_load
                am[pp] += xq.x * wmix[(j4 * 4 + 0) * NP + p]
                        + xq.y * wmix[(j4 * 4 + 1) * NP + p]
                        + xq.z * wmix[(j4 * 4 + 2) * NP + p]
                        + xq.w * wmix[(j4 * 4 + 3) * NP + p];
            }
        }
    }
    __syncthreads();
    // ---- write x half-1 into xs
#pragma unroll
    for (int r = 0; r < 14; r++) {
        int idx  = r * 256 + tid;
        int j    = idx / 112;                    // local 0..31
        int gl   = idx % 112;
        int glst2 = gl + (gl >> 3);
        lds[OFF_XS + (((j >> 2) * 126 + glst2) << 2) + (j & 3)] = xr[r];
    }
    __syncthreads();

    if (bact) {
        const float* wm1 = wmix + 32 * NP;       // j-half 1
#pragma unroll
        for (int j4 = 0; j4 < 8; j4++) {
            float4 xq = xs4[j4 * 126 + glst];
#pragma unroll
            for (int pp = 0; pp < 8; pp++) {
                const int p = p0 + pp;           // wave-uniform -> s_load
                am[pp] += xq.x * wm1[(j4 * 4 + 0) * NP + p]
                        + xq.y * wm1[(j4 * 4 + 1) * NP + p]
                        + xq.z * wm1[(j4 * 4 + 2) * NP + p]
                        + xq.w * wm1[(j4 * 4 + 3) * NP + p];
            }
        }
        // ---- scatter t4 slice into conv layout t4s[(g*16+p)*20 + l+2]
        int g = glB / 14, l = glB % 14;
#pragma unroll
        for (int pp = 0; pp < 8; pp++) {
            t4s[(g * 16 + p0 + pp) * LROW + l + 2] = am[pp];
        }
    }
    __syncthreads();

    // ================= conv phase (verified structure, unchanged) ==========
    const int p  = tid & 15;
    const int jh = tid >> 4;        // 0..15
    const int jb = jh * 2;          // channels j = jb, jb+1

    float acc[NH][2];
#pragma unroll
    for (int n = 0; n < NH; n++) { acc[n][0] = 0.f; acc[n][1] = 0.f; }

    for (int g = 0; g < NG; g++) {
        float row[LROW];
        const float* rp = &t4s[(g * 16 + p) * LROW];
#pragma unroll
        for (int q = 0; q < 5; q++) {
            float4 v = *reinterpret_cast<const float4*>(rp + q * 4);
            row[q * 4 + 0] = v.x; row[q * 4 + 1] = v.y;
            row[q * 4 + 2] = v.z; row[q * 4 + 3] = v.w;
        }
#pragma unroll
        for (int di = 0; di < 5; di++) {
            float2 w = *reinterpret_cast<const float2*>(&w2s[(g * 5 + di) * 32 + jb]);
#pragma unroll
            for (int n = 0; n < NH; n++) {
                float rv = row[n + di];
                acc[n][0] += rv * w.x;
                acc[n][1] += rv * w.y;
            }
        }
        float2 c0 = *reinterpret_cast<const float2*>(&wcs[g * 32 + jb]);
        float2 c1 = *reinterpret_cast<const float2*>(&wcs[256 + g * 32 + jb]);
        float r2 = row[2], r15 = row[15];
        acc[0][0]  -= r2  * c0.x; acc[0][1]  -= r2  * c0.y;
        acc[13][0] -= r15 * c1.x; acc[13][1] -= r15 * c1.y;
    }

    __syncthreads();   // done with t4s/w2s/wcs; reuse lds[0..7680) as out stage

    // ---- stage all 512 channels: addr = c*15 + ((n + 2*(c>>5)) % 15)  (injective)
#pragma unroll
    for (int jj = 0; jj < 2; jj++) {
        int cl  = (jb + jj) * 16 + p;            // 0..511
        int rot = (cl >> 5) * 2;                 // 0,2,..,30 -> mod15 via wrap
        int sb  = cl * 15;
#pragma unroll
        for (int n = 0; n < NH; n++) {
            int rn = n + rot;
            rn -= (rn >= 15) ? 15 : 0;
            rn -= (rn >= 15) ? 15 : 0;           // rot up to 30: two wraps max
            lds[sb + rn] = acc[n][jj];
        }
    }
    __syncthreads();

    // ---- coalesced-ish write: contiguous 14-float runs per channel
    float* ob = out + (size_t)b * 512 * HH + (size_t)o * NH;
#pragma unroll
    for (int r = 0; r < 28; r++) {               // 7168 = 512*14
        int idx = r * 256 + tid;
        int c   = idx / 14;
        int n   = idx % 14;
        int rn  = n + (c >> 5) * 2;
        rn -= (rn >= 15) ? 15 : 0;
        rn -= (rn >= 15) ? 15 : 0;
        ob[(size_t)c * HH + n] = lds[c * 15 + rn];
    }
}

extern "C" void kernel_launch(void* const* d_in, const int* in_sizes, int n_in,
                              void* d_out, int out_size, void* d_ws, size_t ws_size,
                              hipStream_t stream) {
    const float* x     = (const float*)d_in[0];
    const float* wconv = (const float*)d_in[1];
    const float* wmix  = (const float*)d_in[2];
    float* out = (float*)d_out;
    (void)d_ws; (void)ws_size;

    // one block per (b, o)
    fused_kernel<<<NB * NH, 256, 0, stream>>>(x, wconv, wmix, out);
}

// Round 6
// 131.734 us; speedup vs baseline: 1.1175x; 1.0686x over previous
//
#include <hip/hip_runtime.h>

// Problem constants
static constexpr int NB   = 128;   // batch
static constexpr int NCIN = 64;    // input channels
static constexpr int NG   = 8;     // groups
static constexpr int NH   = 14;    // spatial
static constexpr int NP   = 16;    // mixed width
static constexpr int HH   = NH * NH;       // 196
static constexpr int LROW = 20;    // padded t4s row (l in [-2,17])

// LDS layout (float offsets). xs overlaps w2s/wcs IN TIME:
//   xs is live [start .. end of phase B1); w2s/wcs are written after B1
//   (their global loads are issued early into 9 regs/thread).
static constexpr int OFF_T4 = 0;      // [8][16][20] = 2560
static constexpr int OFF_W2 = 2560;   // [8][5][32]  = 1280   (written post-B1)
static constexpr int OFF_WC = 3840;   // [2][8][32]  =  512   (written post-B1)
static constexpr int OFF_XS = 2560;   // [8 j4][126 glst] float4 = 4032 -> ends 6592
static constexpr int LDS_FLOATS = 7680;   // out staging [0,7680) = 30,720 B -> 5 blocks/CU

// ---------------------------------------------------------------------------
// Fully fused kernel. block = (b, o), 256 threads, 5 blocks/CU resident.
//   - x staged in 2 j-halves; per-thread (g,l,glst) computed ONCE (lane128
//     owns one gl; j strides per unrolled iter -> compile-time LDS offsets).
//   - phase B: wave-uniform p-half -> wmix via s_load (no LDS).
//   - wconv loaded early into 9 regs (thread = (g,j)); W2 diag-sums + wcs
//     written to LDS after B1 frees the xs region.
//   - conv: verified 5-tap structure, unchanged.
//   - output: staging rotation (n + 2*(c>>5)) mod 14, stride 15 (injective,
//     bank-spread, pairs contiguous) -> float2 global stores, 16 iters with
//     compile-time rotation per iter.
// ---------------------------------------------------------------------------
__global__ __launch_bounds__(256, 5) void fused_kernel(const float* __restrict__ x,
                                                       const float* __restrict__ wconv,
                                                       const float* __restrict__ wmix,
                                                       float* __restrict__ out) {
    __shared__ __align__(16) float lds[LDS_FLOATS];
    float*  t4s = lds + OFF_T4;
    float*  w2s = lds + OFF_W2;
    float*  wcs = lds + OFF_WC;
    float4* xs4 = reinterpret_cast<float4*>(lds + OFF_XS);

    const int tid   = threadIdx.x;
    const int b     = blockIdx.x / NH;
    const int o     = blockIdx.x % NH;
    const int o_src = (o + NH - 1) % NH;

    const float* xb = x + (size_t)b * (NCIN * NG * HH) + o_src * NH;

    // per-thread staging geometry (computed once)
    const int  lane128 = tid & 127;
    const bool xact    = lane128 < 112;          // gl = lane128
    const int  jrow    = tid >> 7;               // 0/1: j-sub-block within half
    const int  gS      = lane128 / 14;           // 0..7
    const int  lS      = lane128 % 14;           // 0..13
    const int  glst    = lane128 + (lane128 >> 3);   // bank-staggered column

    // ---- issue x half-0 loads (j = 0..31) ----
    float xr[16];
    const float* xb0 = xb + (size_t)(jrow * 16) * (NG * HH) + gS * HH + lS;
    if (xact) {
#pragma unroll
        for (int r = 0; r < 16; r++) xr[r] = xb0[(size_t)r * (NG * HH)];
    }

    // ---- issue wconv loads early: thread = (g,j), 9 coalesced loads ----
    const int gW = tid >> 5, jW = tid & 31;
    float wv9[9];
    {
        const float* wp = wconv + (size_t)(gW * 9) * 32 + jW;
#pragma unroll
        for (int t = 0; t < 9; t++) wv9[t] = wp[t * 32];
    }

    // ---- zero t4s pad columns l2 in {0,1,16,17,18,19} ----
#pragma unroll
    for (int r = 0; r < 3; r++) {                // 768 entries
        int idx = r * 256 + tid;
        int gp  = idx / 6;
        int s   = idx % 6;
        int l2  = (s < 2) ? s : (14 + s);
        t4s[gp * LROW + l2] = 0.f;
    }

    // ---- write x half-0 into xs (base + compile-time offsets) ----
    if (xact) {
        float* xw = lds + OFF_XS + (jrow * 4 * 126 + glst) * 4;
#pragma unroll
        for (int r = 0; r < 16; r++)
            xw[(r >> 2) * (126 * 4) + (r & 3)] = xr[r];
    }
    __syncthreads();

    // ---- prefetch x half-1 (j = 32..63); overlaps with B0 compute ----
    if (xact) {
        const float* xb1 = xb0 + (size_t)32 * (NG * HH);
#pragma unroll
        for (int r = 0; r < 16; r++) xr[r] = xb1[(size_t)r * (NG * HH)];
    }

    // ---- phase B: gl = lane128, wave-uniform p-half p0 = (tid>>7)*8 ----
    const int p0 = __builtin_amdgcn_readfirstlane((tid >> 7) << 3);  // SGPR
    float am[8] = {0.f, 0.f, 0.f, 0.f, 0.f, 0.f, 0.f, 0.f};

    if (xact) {
#pragma unroll
        for (int j4 = 0; j4 < 8; j4++) {
            float4 xq = xs4[j4 * 126 + glst];
#pragma unroll
            for (int pp = 0; pp < 8; pp++) {
                const int p = p0 + pp;           // wave-uniform -> s_load
                am[pp] += xq.x * wmix[(j4 * 4 + 0) * NP + p]
                        + xq.y * wmix[(j4 * 4 + 1) * NP + p]
                        + xq.z * wmix[(j4 * 4 + 2) * NP + p]
                        + xq.w * wmix[(j4 * 4 + 3) * NP + p];
            }
        }
    }
    __syncthreads();
    // ---- write x half-1 into xs ----
    if (xact) {
        float* xw = lds + OFF_XS + (jrow * 4 * 126 + glst) * 4;
#pragma unroll
        for (int r = 0; r < 16; r++)
            xw[(r >> 2) * (126 * 4) + (r & 3)] = xr[r];
    }
    __syncthreads();

    if (xact) {
        const float* wm1 = wmix + 32 * NP;       // j-half 1
#pragma unroll
        for (int j4 = 0; j4 < 8; j4++) {
            float4 xq = xs4[j4 * 126 + glst];
#pragma unroll
            for (int pp = 0; pp < 8; pp++) {
                const int p = p0 + pp;           // wave-uniform -> s_load
                am[pp] += xq.x * wm1[(j4 * 4 + 0) * NP + p]
                        + xq.y * wm1[(j4 * 4 + 1) * NP + p]
                        + xq.z * wm1[(j4 * 4 + 2) * NP + p]
                        + xq.w * wm1[(j4 * 4 + 3) * NP + p];
            }
        }
        // ---- scatter t4 slice into conv layout t4s[(g*16+p)*20 + l+2] ----
#pragma unroll
        for (int pp = 0; pp < 8; pp++) {
            t4s[(gS * 16 + p0 + pp) * LROW + lS + 2] = am[pp];
        }
    }
    __syncthreads();   // all xs reads done -> w2s/wcs region free

    // ---- W2 diag-sums + corrections from regs (zero divisions) ----
    {
        float d0 = wv9[0];                       // w00
        float d1 = wv9[1] + wv9[3];              // w01+w10
        float d2 = wv9[2] + wv9[4] + wv9[6];     // w02+w11+w20
        float d3 = wv9[5] + wv9[7];              // w12+w21
        float d4 = wv9[8];                       // w22
        float* wp2 = w2s + gW * 160 + jW;
        wp2[0]   = d0;
        wp2[32]  = d1;
        wp2[64]  = d2;
        wp2[96]  = d3;
        wp2[128] = d4;
        wcs[gW * 32 + jW]       = wv9[2];        // w[0][2]
        wcs[256 + gW * 32 + jW] = wv9[6];        // w[2][0]
    }
    __syncthreads();

    // ================= conv phase (verified structure, unchanged) ==========
    const int p  = tid & 15;
    const int jh = tid >> 4;        // 0..15
    const int jb = jh * 2;          // channels j = jb, jb+1

    float acc[NH][2];
#pragma unroll
    for (int n = 0; n < NH; n++) { acc[n][0] = 0.f; acc[n][1] = 0.f; }

    for (int g = 0; g < NG; g++) {
        float row[LROW];
        const float* rp = &t4s[(g * 16 + p) * LROW];
#pragma unroll
        for (int q = 0; q < 5; q++) {
            float4 v = *reinterpret_cast<const float4*>(rp + q * 4);
            row[q * 4 + 0] = v.x; row[q * 4 + 1] = v.y;
            row[q * 4 + 2] = v.z; row[q * 4 + 3] = v.w;
        }
#pragma unroll
        for (int di = 0; di < 5; di++) {
            float2 w = *reinterpret_cast<const float2*>(&w2s[(g * 5 + di) * 32 + jb]);
#pragma unroll
            for (int n = 0; n < NH; n++) {
                float rv = row[n + di];
                acc[n][0] += rv * w.x;
                acc[n][1] += rv * w.y;
            }
        }
        float2 c0 = *reinterpret_cast<const float2*>(&wcs[g * 32 + jb]);
        float2 c1 = *reinterpret_cast<const float2*>(&wcs[256 + g * 32 + jb]);
        float r2 = row[2], r15 = row[15];
        acc[0][0]  -= r2  * c0.x; acc[0][1]  -= r2  * c0.y;
        acc[13][0] -= r15 * c1.x; acc[13][1] -= r15 * c1.y;
    }

    __syncthreads();   // done with t4s/w2s/wcs; reuse lds[0..7680) as out stage

    // ---- stage 512 channels: addr = c*15 + ((n + 2*(c>>5)) mod 14)  (injective,
    //      slot 14 unused; rotation de-conflicts dc=32 writer lanes) ----
    {
        int rotw = jh * 2;                       // c>>5 == jh for both jj
        rotw -= (rotw >= 14) ? 14 : 0;
        rotw -= (rotw >= 14) ? 14 : 0;           // 2jh <= 30 -> two wraps max
#pragma unroll
        for (int jj = 0; jj < 2; jj++) {
            int sb = ((jb + jj) * 16 + p) * 15;
#pragma unroll
            for (int n = 0; n < NH; n++) {
                int rn = n + rotw;               // <= 13+12
                rn -= (rn >= 14) ? 14 : 0;
                lds[sb + rn] = acc[n][jj];
            }
        }
    }
    __syncthreads();

    // ---- writeout: thread = (cbase = tid>>3, k = tid&7<7), float2 stores ----
    {
        const int  k7   = tid & 7;
        const bool kact = k7 < 7;
        const int  cb   = tid >> 3;              // 0..31
        float* ob = out + (size_t)b * 512 * HH + (size_t)o * NH;
        if (kact) {
#pragma unroll
            for (int r = 0; r < 16; r++) {
                int c   = cb + 32 * r;           // c>>5 == r
                int rot = (2 * r) % 14;          // compile-time per iter
                int rn  = 2 * k7 + rot;          // <= 24
                rn -= (rn >= 14) ? 14 : 0;
                float v0 = lds[c * 15 + rn];
                float v1 = lds[c * 15 + rn + 1]; // rn even <=12 -> no wrap
                *reinterpret_cast<float2*>(ob + (size_t)c * HH + 2 * k7) =
                    make_float2(v0, v1);
            }
        }
    }
}

extern "C" void kernel_launch(void* const* d_in, const int* in_sizes, int n_in,
                              void* d_out, int out_size, void* d_ws, size_t ws_size,
                              hipStream_t stream) {
    const float* x     = (const float*)d_in[0];
    const float* wconv = (const float*)d_in[1];
    const float* wmix  = (const float*)d_in[2];
    float* out = (float*)d_out;
    (void)d_ws; (void)ws_size;

    // one block per (b, o)
    fused_kernel<<<NB * NH, 256, 0, stream>>>(x, wconv, wmix, out);
}